// Round 10
// baseline (267.147 us; speedup 1.0000x reference)
//
#include <hip/hip_runtime.h>
#include <hip/hip_bf16.h>

// SVXSoftmax: cos = norm(input) @ norm(weight)^T ; margin transform ; *32
// B=512, D=512, C=100000.  out[512][100000] f32.
//
// r10: FUSED single-GEMM = r9-gemm2 lean skeleton + in-loop f32->bf16 W convert.
//  - prep: gt + bf16-normalized input packed in MFMA fragment order (512KB, L2).
//  - gemm: 256 thr / 4 waves (2x2), tile 128M x 128N, BK=32, dbuf, 1 barrier/step.
//    A: packed bf16 via linear gl16 (zero conflicts, r9-proven).
//    B: raw f32 W via gl16 with PRE-SWIZZLED global source (rule #21; r8-verified):
//       LDS[row][pl] = G[row][pl ^ (row&7)]  (16B pieces) -> fragment reads are
//       bank-BALANCED (8-way uniform across all groups = full LDS BW).
//    cvt at fragment read via native __float22bfloat162_rn (m240: compiler
//    codegen beats hand-written; RNE = proven numerics), 2x redundancy only.
//    sumsq by wm==0 wave pair from loaded values; invnorm applied post-MFMA.
//    48.5KB LDS -> 3 blocks/CU; __launch_bounds__(256,4) pins VGPR<=128
//    (m69 cliff at 129 -> 8 waves/CU is the guarded failure mode).
//  - grid (4 bm, 782 bn), bm fastest: 4 siblings share each W tile via L2/L3
//    (r1/r9-proven: FETCH stays ~205MB).

#define S_SCALE 32.0f
#define MARGIN  0.35f
#define T_BOOST 0.2f
#define EPSN    1e-12f

constexpr int Bn = 512;      // batch
constexpr int Dn = 512;      // dim
constexpr int Cn = 100000;   // classes

typedef __attribute__((ext_vector_type(8))) short bf16x8;
typedef __attribute__((ext_vector_type(4))) float f32x4;

static __device__ inline unsigned short f32_bf16(float f) {
    unsigned int u = __float_as_uint(f);
    u += 0x7FFFu + ((u >> 16) & 1u);     // round-to-nearest-even
    return (unsigned short)(u >> 16);
}

static __device__ __forceinline__ unsigned int cvt2(float a, float b) {
    __hip_bfloat162 h = __float22bfloat162_rn({a, b});
    return *reinterpret_cast<unsigned int*>(&h);
}

typedef __attribute__((address_space(1))) const unsigned int GUI;
typedef __attribute__((address_space(3))) unsigned int LUI;
static __device__ __forceinline__ void gl16(const void* g, void* l) {
    __builtin_amdgcn_global_load_lds((GUI*)g, (LUI*)l, 16, 0, 0);
}

// fragment packing: byte = (g<<14) + (s<<10) + (lane<<4) + (k&7)*2
//   g = row>>4, s = k>>5, lane = ((k>>3)&3)*16 + (row&15)
__global__ __launch_bounds__(256) void prep_kernel(const float* __restrict__ in,
                                                   const float* __restrict__ w,
                                                   const int* __restrict__ label,
                                                   float* __restrict__ gt,
                                                   unsigned short* __restrict__ in_p) {
    int b = blockIdx.x, t = threadIdx.x;
    const float* irow = in + (size_t)b * Dn;
    int lab = label[b];
    const float* wrow = w + (size_t)lab * Dn;
    int c = 2 * t;
    float xa = irow[c], xb = irow[c + 1];
    float ya = wrow[c], yb = wrow[c + 1];
    float s_ii = xa*xa + xb*xb, s_ww = ya*ya + yb*yb, s_iw = xa*ya + xb*yb;
    #pragma unroll
    for (int off = 32; off; off >>= 1) {
        s_ii += __shfl_xor(s_ii, off);
        s_ww += __shfl_xor(s_ww, off);
        s_iw += __shfl_xor(s_iw, off);
    }
    __shared__ float r0[4], r1[4], r2[4], bc[1];
    int wid = t >> 6;
    if ((t & 63) == 0) { r0[wid] = s_ii; r1[wid] = s_ww; r2[wid] = s_iw; }
    __syncthreads();
    if (t == 0) {
        float a  = r0[0] + r0[1] + r0[2] + r0[3];
        float cc = r1[0] + r1[1] + r1[2] + r1[3];
        float d  = r2[0] + r2[1] + r2[2] + r2[3];
        float inv_i = 1.0f / fmaxf(sqrtf(a), EPSN);
        float g = d * inv_i / fmaxf(sqrtf(cc), EPSN);
        gt[b] = fminf(fmaxf(g, -1.0f), 1.0f);
        bc[0] = inv_i;
    }
    __syncthreads();
    float inv_i = bc[0];
    int g = b >> 4, l15 = b & 15;
    int s = t >> 4, lk = (t >> 2) & 3, j2 = (t & 3) * 4;
    int lane = lk * 16 + l15;
    unsigned int off = (unsigned)((g << 14) + (s << 10) + (lane << 4)) + j2;
    unsigned int h0 = f32_bf16(xa * inv_i), h1 = f32_bf16(xb * inv_i);
    *(unsigned int*)((char*)in_p + off) = h0 | (h1 << 16);
}

// ---------------- fused convert+GEMM+margin ----------------
__global__ __launch_bounds__(256, 4) void gemm_kernel(const unsigned short* __restrict__ in_p,
                                                      const float* __restrict__ w,
                                                      const float* __restrict__ gt,
                                                      const int* __restrict__ label,
                                                      float* __restrict__ out) {
    __shared__ __align__(16) char Ab[2][8192];    // bf16 A, fragment-packed
    __shared__ __align__(16) char Bb[2][16384];   // f32 W, rows 128B, pieces swizzled
    __shared__ float inv_s[128];

    int t = threadIdx.x, wv = t >> 6, lane = t & 63;
    int wm = wv >> 1, wn = wv & 1;
    int l15 = lane & 15, lk = lane >> 4;
    int bm = blockIdx.x, bn = blockIdx.y;

    // ---- staging addresses ----
    // A: wave wv stages groups {wv*2, wv*2+1}
    const char* asrc0 = (const char*)in_p + ((size_t)(bm * 8 + wv * 2)     << 14) + (lane << 4);
    const char* asrc1 = (const char*)in_p + ((size_t)(bm * 8 + wv * 2 + 1) << 14) + (lane << 4);
    // B: wave wv stages rows [wv*32, wv*32+32) in 4 chunks of 8 rows
    int rsub = lane >> 3;                        // row within 8-row chunk
    int pg   = (lane & 7) ^ rsub;                // pre-swizzled global 16B piece
    const char* bsrc[4];
    #pragma unroll
    for (int j = 0; j < 4; ++j) {
        int rloc = wv * 32 + j * 8 + rsub;
        int rg = bn * 128 + rloc; if (rg >= Cn) rg = Cn - 1;
        bsrc[j] = (const char*)w + (size_t)rg * 2048 + pg * 16;
    }

    #define STAGE(kt, buf)                                                      \
        do {                                                                    \
            gl16(asrc0 + ((kt) << 10), &Ab[buf][(wv*2)   * 1024 + lane*16]);    \
            gl16(asrc1 + ((kt) << 10), &Ab[buf][(wv*2+1) * 1024 + lane*16]);    \
            gl16(bsrc[0] + (kt) * 128, &Bb[buf][(wv*4)   * 1024 + lane*16]);    \
            gl16(bsrc[1] + (kt) * 128, &Bb[buf][(wv*4+1) * 1024 + lane*16]);    \
            gl16(bsrc[2] + (kt) * 128, &Bb[buf][(wv*4+2) * 1024 + lane*16]);    \
            gl16(bsrc[3] + (kt) * 128, &Bb[buf][(wv*4+3) * 1024 + lane*16]);    \
        } while (0)

    f32x4 acc[4][4];
    #pragma unroll
    for (int m = 0; m < 4; ++m)
        #pragma unroll
        for (int n = 0; n < 4; ++n) acc[m][n] = (f32x4){0.f, 0.f, 0.f, 0.f};
    float ssq[4] = {0.f, 0.f, 0.f, 0.f};

    STAGE(0, 0);
    __syncthreads();

    #pragma unroll 2
    for (int kt = 0; kt < 16; ++kt) {
        int cur = kt & 1;
        if (kt < 15) STAGE(kt + 1, cur ^ 1);

        // A fragments (already bf16 packed)
        bf16x8 ar[4];
        #pragma unroll
        for (int mf = 0; mf < 4; ++mf)
            ar[mf] = *(const bf16x8*)&Ab[cur][(wm * 4 + mf) * 1024 + lane * 16];

        // B fragments: de-swizzled f32 reads + native-RNE cvt (+ sumsq on wm==0)
        bf16x8 bfrag[4];
        #pragma unroll
        for (int nf = 0; nf < 4; ++nf) {
            int r = wn * 64 + nf * 16 + l15;
            const char* rb = &Bb[cur][r * 128];
            int q0 = (2 * lk) ^ (r & 7), q1 = (2 * lk + 1) ^ (r & 7);
            f32x4 v0 = *(const f32x4*)(rb + q0 * 16);
            f32x4 v1 = *(const f32x4*)(rb + q1 * 16);
            union { bf16x8 v8; unsigned int u[4]; } uu;
            uu.u[0] = cvt2(v0[0], v0[1]);
            uu.u[1] = cvt2(v0[2], v0[3]);
            uu.u[2] = cvt2(v1[0], v1[1]);
            uu.u[3] = cvt2(v1[2], v1[3]);
            bfrag[nf] = uu.v8;
            if (wm == 0)
                ssq[nf] += v0[0]*v0[0] + v0[1]*v0[1] + v0[2]*v0[2] + v0[3]*v0[3]
                         + v1[0]*v1[0] + v1[1]*v1[1] + v1[2]*v1[2] + v1[3]*v1[3];
        }

        #pragma unroll
        for (int mf = 0; mf < 4; ++mf)
            #pragma unroll
            for (int nf = 0; nf < 4; ++nf)
                acc[mf][nf] = __builtin_amdgcn_mfma_f32_16x16x32_bf16(ar[mf], bfrag[nf], acc[mf][nf], 0, 0, 0);

        __syncthreads();
    }

    // ---- invnorm from accumulated sumsq (wm==0 pair owns all 128 rows) ----
    if (wm == 0) {
        #pragma unroll
        for (int nf = 0; nf < 4; ++nf) {
            float s = ssq[nf];
            s += __shfl_xor(s, 16); s += __shfl_xor(s, 32);   // reduce over lk
            if (lk == 0) inv_s[wn * 64 + nf * 16 + l15] = 1.0f / fmaxf(sqrtf(s), EPSN);
        }
    }
    __syncthreads();

    float invc[4];
    #pragma unroll
    for (int nf = 0; nf < 4; ++nf) invc[nf] = inv_s[wn * 64 + nf * 16 + l15];

    // ---- epilogue: invnorm, clamp, margin, label scatter, scale ----
    #pragma unroll
    for (int mf = 0; mf < 4; ++mf) {
        #pragma unroll
        for (int r = 0; r < 4; ++r) {
            int b_row = bm * 128 + wm * 64 + mf * 16 + lk * 4 + r;
            float thr = gt[b_row] - MARGIN;
            int lab   = label[b_row];
            float gv  = thr * S_SCALE;
            size_t obase = (size_t)b_row * Cn;
            #pragma unroll
            for (int nf = 0; nf < 4; ++nf) {
                int c = bn * 128 + wn * 64 + nf * 16 + l15;
                if (c < Cn) {
                    float cosv = acc[mf][nf][r] * invc[nf];
                    cosv = fminf(fmaxf(cosv, -1.0f), 1.0f);
                    float o = (cosv > thr) ? ((T_BOOST + 1.0f) * cosv + T_BOOST) : cosv;
                    o *= S_SCALE;
                    if (c == lab) o = gv;
                    out[obase + c] = o;
                }
            }
        }
    }
}

extern "C" void kernel_launch(void* const* d_in, const int* in_sizes, int n_in,
                              void* d_out, int out_size, void* d_ws, size_t ws_size,
                              hipStream_t stream) {
    const float* in  = (const float*)d_in[0];
    const float* w   = (const float*)d_in[1];
    const int* label = (const int*)d_in[2];
    float* out = (float*)d_out;

    char* ws = (char*)d_ws;
    float* gt            = (float*)ws;                   // 512 f32
    unsigned short* in_p = (unsigned short*)(ws + 4096); // packed 512KB

    prep_kernel<<<dim3(Bn), dim3(256), 0, stream>>>(in, w, label, gt, in_p);
    dim3 grid(4, (Cn + 127) / 128);   // bm fastest: siblings share W tile via L2/L3
    gemm_kernel<<<grid, dim3(256), 0, stream>>>(in_p, w, gt, label, out);
}

// Round 11
// 206.295 us; speedup vs baseline: 1.2950x; 1.2950x over previous
//
#include <hip/hip_runtime.h>
#include <hip/hip_bf16.h>

// SVXSoftmax: cos = norm(input) @ norm(weight)^T ; margin transform ; *32
// B=512, D=512, C=100000.  out[512][100000] f32.
//
// r11: fused single-GEMM on the r9 lean skeleton + 3 fixes:
//  1) T1 XCD-chunked swizzle: 3128 blocks = 8 XCDs x 391; each XCD gets a
//     contiguous bn-range with all 4 bm-siblings -> W fetched once (r10's
//     FETCH=2xW came from siblings on different XCDs).
//  2) convert-once B staging: thread owns (row, K-half); global f32 -> regs,
//     ONE cvt per element, ds_write_b128 directly in MFMA-fragment layout
//     (uniform bank spread). sumsq per-thread + shfl_xor(1) (lane pair = row).
//  3) T4 counted-vmcnt barrier: per step {gl16 A(kt+1); issue L(kt+2);
//     MFMA(kt); cvt+write L(kt+1); s_waitcnt vmcnt(4); s_barrier} -> the 4
//     newest outstanding = L(kt+2) REGISTER loads, legal across the barrier
//     (dist-2 prefetch, no LDS race; gl16s are older => drained).
//  acc in AGPR; ~80 VGPR; 33KB LDS -> 4 blocks/CU; 1 barrier/step.

#define S_SCALE 32.0f
#define MARGIN  0.35f
#define T_BOOST 0.2f
#define EPSN    1e-12f

constexpr int Bn = 512;      // batch
constexpr int Dn = 512;      // dim
constexpr int Cn = 100000;   // classes
constexpr int NBN = (Cn + 127) / 128;    // 782 column tiles
constexpr int NWG = 4 * NBN;             // 3128 = 8 * 391
constexpr int QX  = NWG / 8;             // 391 blocks per XCD

typedef __attribute__((ext_vector_type(8))) short bf16x8;
typedef __attribute__((ext_vector_type(4))) float f32x4;

static __device__ inline unsigned short f32_bf16(float f) {
    unsigned int u = __float_as_uint(f);
    u += 0x7FFFu + ((u >> 16) & 1u);     // round-to-nearest-even
    return (unsigned short)(u >> 16);
}

static __device__ __forceinline__ unsigned int cvt2(float a, float b) {
    __hip_bfloat162 h = __float22bfloat162_rn({a, b});
    return *reinterpret_cast<unsigned int*>(&h);
}

typedef __attribute__((address_space(1))) const unsigned int GUI;
typedef __attribute__((address_space(3))) unsigned int LUI;
static __device__ __forceinline__ void gl16(const void* g, void* l) {
    __builtin_amdgcn_global_load_lds((GUI*)g, (LUI*)l, 16, 0, 0);
}

// counted barrier: drain LDS ops + all but newest N vmem ops, then barrier.
#define CBAR(N) do {                                                          \
    asm volatile("s_waitcnt vmcnt(" #N ") lgkmcnt(0)\n\ts_barrier" ::: "memory"); \
    __builtin_amdgcn_sched_barrier(0);                                        \
} while (0)

// fragment packing: byte = (g<<14) + (s<<10) + (lane<<4) + (k&7)*2
//   g = row>>4, s = k>>5, lane = ((k>>3)&3)*16 + (row&15)
__global__ __launch_bounds__(256) void prep_kernel(const float* __restrict__ in,
                                                   const float* __restrict__ w,
                                                   const int* __restrict__ label,
                                                   float* __restrict__ gt,
                                                   unsigned short* __restrict__ in_p) {
    int b = blockIdx.x, t = threadIdx.x;
    const float* irow = in + (size_t)b * Dn;
    int lab = label[b];
    const float* wrow = w + (size_t)lab * Dn;
    int c = 2 * t;
    float xa = irow[c], xb = irow[c + 1];
    float ya = wrow[c], yb = wrow[c + 1];
    float s_ii = xa*xa + xb*xb, s_ww = ya*ya + yb*yb, s_iw = xa*ya + xb*yb;
    #pragma unroll
    for (int off = 32; off; off >>= 1) {
        s_ii += __shfl_xor(s_ii, off);
        s_ww += __shfl_xor(s_ww, off);
        s_iw += __shfl_xor(s_iw, off);
    }
    __shared__ float r0[4], r1[4], r2[4], bc[1];
    int wid = t >> 6;
    if ((t & 63) == 0) { r0[wid] = s_ii; r1[wid] = s_ww; r2[wid] = s_iw; }
    __syncthreads();
    if (t == 0) {
        float a  = r0[0] + r0[1] + r0[2] + r0[3];
        float cc = r1[0] + r1[1] + r1[2] + r1[3];
        float d  = r2[0] + r2[1] + r2[2] + r2[3];
        float inv_i = 1.0f / fmaxf(sqrtf(a), EPSN);
        float g = d * inv_i / fmaxf(sqrtf(cc), EPSN);
        gt[b] = fminf(fmaxf(g, -1.0f), 1.0f);
        bc[0] = inv_i;
    }
    __syncthreads();
    float inv_i = bc[0];
    int g = b >> 4, l15 = b & 15;
    int s = t >> 4, lk = (t >> 2) & 3, j2 = (t & 3) * 4;
    int lane = lk * 16 + l15;
    unsigned int off = (unsigned)((g << 14) + (s << 10) + (lane << 4)) + j2;
    unsigned int h0 = f32_bf16(xa * inv_i), h1 = f32_bf16(xb * inv_i);
    *(unsigned int*)((char*)in_p + off) = h0 | (h1 << 16);
}

// ---------------- fused convert-once GEMM + margin ----------------
__global__ __launch_bounds__(256, 4) void gemm_kernel(const unsigned short* __restrict__ in_p,
                                                      const float* __restrict__ w,
                                                      const float* __restrict__ gt,
                                                      const int* __restrict__ label,
                                                      float* __restrict__ out) {
    __shared__ __align__(16) char Ab[2][8192];    // bf16 A, fragment-packed
    __shared__ __align__(16) char Bb[2][8192];    // bf16 B, fragment-packed
    __shared__ float inv_s[128];

    int t = threadIdx.x, wv = t >> 6, lane = t & 63;
    int wm = wv >> 1, wn = wv & 1;
    int l15 = lane & 15, lk = lane >> 4;

    // XCD-chunked swizzle (T1): each XCD owns contiguous work, bm fastest.
    int bid = blockIdx.x;
    int work = (bid & 7) * QX + (bid >> 3);
    int bm = work & 3, bn = work >> 2;

    // ---- A staging (gl16, r9-proven) ----
    const char* asrc0 = (const char*)in_p + ((size_t)(bm * 8 + wv * 2)     << 14) + (lane << 4);
    const char* asrc1 = (const char*)in_p + ((size_t)(bm * 8 + wv * 2 + 1) << 14) + (lane << 4);

    // ---- B staging map: thread t -> row rl = t>>1, K-half khalf = t&1 ----
    int rl = t >> 1, khalf = t & 1;
    int rg = bn * 128 + rl; if (rg >= Cn) rg = Cn - 1;
    const char* bW = (const char*)w + (size_t)rg * 2048 + khalf * 64;   // 64B per step
    // fragment-layout write base (buffer-relative), second b128 at +256
    int wb1 = ((rl >> 4) << 10) + (((khalf * 2) * 16 + (rl & 15)) << 4);

    f32x4 acc[4][4];
    #pragma unroll
    for (int m = 0; m < 4; ++m)
        #pragma unroll
        for (int n = 0; n < 4; ++n) acc[m][n] = (f32x4){0.f, 0.f, 0.f, 0.f};

    float ss = 0.f;
    f32x4 rB[2][4];

    #define BLOAD(set, kt)                                                    \
        do {                                                                  \
            rB[set][0] = *(const f32x4*)(bW + (kt) * 128);                    \
            rB[set][1] = *(const f32x4*)(bW + (kt) * 128 + 16);               \
            rB[set][2] = *(const f32x4*)(bW + (kt) * 128 + 32);               \
            rB[set][3] = *(const f32x4*)(bW + (kt) * 128 + 48);               \
        } while (0)

    #define BCVT(set, buf)                                                    \
        do {                                                                  \
            f32x4 v0 = rB[set][0], v1 = rB[set][1], v2 = rB[set][2], v3 = rB[set][3]; \
            ss += v0[0]*v0[0] + v0[1]*v0[1] + v0[2]*v0[2] + v0[3]*v0[3]       \
                + v1[0]*v1[0] + v1[1]*v1[1] + v1[2]*v1[2] + v1[3]*v1[3]       \
                + v2[0]*v2[0] + v2[1]*v2[1] + v2[2]*v2[2] + v2[3]*v2[3]       \
                + v3[0]*v3[0] + v3[1]*v3[1] + v3[2]*v3[2] + v3[3]*v3[3];      \
            union { bf16x8 v8; unsigned int u[4]; } h1, h2;                   \
            h1.u[0] = cvt2(v0[0], v0[1]); h1.u[1] = cvt2(v0[2], v0[3]);       \
            h1.u[2] = cvt2(v1[0], v1[1]); h1.u[3] = cvt2(v1[2], v1[3]);       \
            h2.u[0] = cvt2(v2[0], v2[1]); h2.u[1] = cvt2(v2[2], v2[3]);       \
            h2.u[2] = cvt2(v3[0], v3[1]); h2.u[3] = cvt2(v3[2], v3[3]);       \
            *(bf16x8*)(&Bb[buf][wb1])       = h1.v8;                          \
            *(bf16x8*)(&Bb[buf][wb1 + 256]) = h2.v8;                          \
        } while (0)

    // ---- prologue: step0 -> buf0; issue L1 ----
    BLOAD(0, 0);
    gl16(asrc0, &Ab[0][(wv * 2)     * 1024 + lane * 16]);
    gl16(asrc1, &Ab[0][(wv * 2 + 1) * 1024 + lane * 16]);
    BLOAD(1, 1);
    BCVT(0, 0);
    CBAR(4);   // drain A0 gl16 + B0 ds_writes; L1 (newest 4) stays in flight

    // ---- main loop: 16 K-steps, 1 counted barrier per step ----
    #pragma unroll
    for (int kt = 0; kt < 16; ++kt) {
        const int cur = kt & 1, nxt = cur ^ 1;
        if (kt < 15) {                      // gl16 A(kt+1) FIRST (older than L)
            gl16(asrc0 + ((kt + 1) << 10), &Ab[nxt][(wv * 2)     * 1024 + lane * 16]);
            gl16(asrc1 + ((kt + 1) << 10), &Ab[nxt][(wv * 2 + 1) * 1024 + lane * 16]);
        }
        if (kt < 14) BLOAD(cur, kt + 2);    // L(kt+2): the 4 newest vmem ops

        bf16x8 ar[4], br[4];
        #pragma unroll
        for (int mf = 0; mf < 4; ++mf)
            ar[mf] = *(const bf16x8*)&Ab[cur][(wm * 4 + mf) * 1024 + lane * 16];
        #pragma unroll
        for (int nf = 0; nf < 4; ++nf)
            br[nf] = *(const bf16x8*)&Bb[cur][(wn * 4 + nf) * 1024 + lane * 16];

        #pragma unroll
        for (int mf = 0; mf < 4; ++mf)
            #pragma unroll
            for (int nf = 0; nf < 4; ++nf)
                acc[mf][nf] = __builtin_amdgcn_mfma_f32_16x16x32_bf16(ar[mf], br[nf], acc[mf][nf], 0, 0, 0);

        if (kt < 15) BCVT(nxt, nxt);        // cvt+write L(kt+1) -> buf nxt

        if (kt < 15) {
            if (kt < 14) CBAR(4);           // keep L(kt+2) in flight
            else         CBAR(0);           // kt==14: drain A15 gl16
        }
    }
    __syncthreads();

    // ---- invnorm: lane pair (t, t^1) holds the same row ----
    ss += __shfl_xor(ss, 1);
    if (khalf == 0) inv_s[rl] = 1.0f / fmaxf(sqrtf(ss), EPSN);
    __syncthreads();

    float invc[4];
    #pragma unroll
    for (int nf = 0; nf < 4; ++nf) invc[nf] = inv_s[wn * 64 + nf * 16 + l15];

    // ---- epilogue: invnorm, clamp, margin, label scatter, scale ----
    #pragma unroll
    for (int mf = 0; mf < 4; ++mf) {
        #pragma unroll
        for (int r = 0; r < 4; ++r) {
            int b_row = bm * 128 + wm * 64 + mf * 16 + lk * 4 + r;
            float thr = gt[b_row] - MARGIN;
            int lab   = label[b_row];
            float gv  = thr * S_SCALE;
            size_t obase = (size_t)b_row * Cn;
            #pragma unroll
            for (int nf = 0; nf < 4; ++nf) {
                int c = bn * 128 + wn * 64 + nf * 16 + l15;
                if (c < Cn) {
                    float cosv = acc[mf][nf][r] * invc[nf];
                    cosv = fminf(fmaxf(cosv, -1.0f), 1.0f);
                    float o = (cosv > thr) ? ((T_BOOST + 1.0f) * cosv + T_BOOST) : cosv;
                    o *= S_SCALE;
                    if (c == lab) o = gv;
                    out[obase + c] = o;
                }
            }
        }
    }
}

extern "C" void kernel_launch(void* const* d_in, const int* in_sizes, int n_in,
                              void* d_out, int out_size, void* d_ws, size_t ws_size,
                              hipStream_t stream) {
    const float* in  = (const float*)d_in[0];
    const float* w   = (const float*)d_in[1];
    const int* label = (const int*)d_in[2];
    float* out = (float*)d_out;

    char* ws = (char*)d_ws;
    float* gt            = (float*)ws;                   // 512 f32
    unsigned short* in_p = (unsigned short*)(ws + 4096); // packed 512KB

    prep_kernel<<<dim3(Bn), dim3(256), 0, stream>>>(in, w, label, gt, in_p);
    gemm_kernel<<<dim3(NWG), dim3(256), 0, stream>>>(in_p, w, gt, label, out);
}